// Round 6
// baseline (11113.194 us; speedup 1.0000x reference)
//
#include <hip/hip_runtime.h>
#include <stdint.h>
#include <math.h>

// Problem constants (match reference)
#define BB 128
#define NN 2048
#define DD 2
#define ROWLEN (2 + NN * DD + 5)   // 4103
#define SIGMA_C 0.001f
#define HALF_CNT 262144u           // B*N*D / 2

#define TPB 128                    // threads per block (2 waves)

// SSA vector types (subscripts -> insert/extractelement, never allocas).
typedef float v8f  __attribute__((ext_vector_type(8)));
typedef float v16f __attribute__((ext_vector_type(16)));
typedef float v32f __attribute__((ext_vector_type(32)));

// elu derivative from elu output: d = (z>0) ? 1 : exp(z); for z<=0,
// h = exp(z)-1  =>  d = h+1 (<=1 ulp). h>0 <=> z>0 (monotone).
#define DFROMH(h) ((h) > 0.0f ? 1.0f : (h) + 1.0f)

__device__ __forceinline__ uint32_t rotl32(uint32_t v, uint32_t r) {
  return (v << r) | (v >> (32u - r));
}

// JAX threefry2x32 (20 rounds), matches jax/_src/prng.py
__device__ __forceinline__ void tf2x32(uint32_t k0, uint32_t k1,
                                       uint32_t x0, uint32_t x1,
                                       uint32_t& o0, uint32_t& o1) {
  uint32_t k2 = k0 ^ k1 ^ 0x1BD11BDAu;
  x0 += k0; x1 += k1;
#define TF_R(r) { x0 += x1; x1 = rotl32(x1, r); x1 ^= x0; }
  TF_R(13) TF_R(15) TF_R(26) TF_R(6)   x0 += k1; x1 += k2 + 1u;
  TF_R(17) TF_R(29) TF_R(16) TF_R(24)  x0 += k2; x1 += k0 + 2u;
  TF_R(13) TF_R(15) TF_R(26) TF_R(6)   x0 += k0; x1 += k1 + 3u;
  TF_R(17) TF_R(29) TF_R(16) TF_R(24)  x0 += k1; x1 += k2 + 4u;
  TF_R(13) TF_R(15) TF_R(26) TF_R(6)   x0 += k2; x1 += k0 + 5u;
#undef TF_R
  o0 = x0; o1 = x1;
}

// XLA f32 ErfInv (Giles 2012 polynomial) — what lax.erf_inv lowers to
__device__ __forceinline__ float erfinv_f32(float x) {
  float w = -log1pf(-(x * x));
  float p;
  if (w < 5.0f) {
    w = w - 2.5f;
    p = 2.81022636e-08f;
    p = fmaf(p, w, 3.43273939e-07f);
    p = fmaf(p, w, -3.5233877e-06f);
    p = fmaf(p, w, -4.39150654e-06f);
    p = fmaf(p, w, 0.00021858087f);
    p = fmaf(p, w, -0.00125372503f);
    p = fmaf(p, w, -0.00417768164f);
    p = fmaf(p, w, 0.246640727f);
    p = fmaf(p, w, 1.50140941f);
  } else {
    w = sqrtf(w) - 3.0f;
    p = -0.000200214257f;
    p = fmaf(p, w, 0.000100950558f);
    p = fmaf(p, w, 0.00134934322f);
    p = fmaf(p, w, -0.00367342844f);
    p = fmaf(p, w, 0.00573950773f);
    p = fmaf(p, w, -0.0076224613f);
    p = fmaf(p, w, 0.00943887047f);
    p = fmaf(p, w, 1.00167406f);
    p = fmaf(p, w, 2.83297682f);
  }
  return p * x;
}

// jax.random.normal for one flat element index f under key (k0,k1)
__device__ __forceinline__ float jax_normal_elem(uint32_t k0, uint32_t k1,
                                                 uint32_t f) {
  uint32_t o0, o1, bits;
  if (f < HALF_CNT) {
    tf2x32(k0, k1, f, f + HALF_CNT, o0, o1);
    bits = o0;
  } else {
    tf2x32(k0, k1, f - HALF_CNT, f, o0, o1);
    bits = o1;
  }
  float u01 = __uint_as_float((bits >> 9) | 0x3f800000u) - 1.0f;
  const float lo = -0.99999994f;           // nextafter(-1, 0) in f32
  float v = fmaxf(lo, fmaf(u01, 2.0f, lo));
  return 1.41421356237309515f * erfinv_f32(v);
}

// LDS stash: h2 (32) + h3 (32) + h1 (16) = 80 floats/thread.
// 80 * 128 threads * 4 B = 40 KB/block -> 4 blocks/CU (LDS-capped, 2 waves/EU).
// Layout [slot][tid]: lane-consecutive -> 2-way bank aliasing only (free).
// Private per-thread columns: no barriers.
#define SLOT_H2 0
#define SLOT_H3 32
#define SLOT_H1 64
#define LDS_FLOATS (80 * TPB)

// R1-R5 lesson: the RA grants ~84-96 VGPRs regardless of launch_bounds /
// amdgpu_waves_per_eu; demand must fit under that. This version's structural
// peak live set is ~79 (8-wide producer-consumer fusion + LDS stash of all
// fwd->bwd activations), so no allocator fight is needed.
__global__ __launch_bounds__(TPB, 2) void phinn_kernel(
    const float* __restrict__ x,
    const float* __restrict__ W1, const float* __restrict__ b1,
    const float* __restrict__ W2, const float* __restrict__ b2,
    const float* __restrict__ W3, const float* __restrict__ b3,
    const float* __restrict__ W4, const float* __restrict__ b4,
    const float* __restrict__ W5, const float* __restrict__ b5,
    const float* __restrict__ Wt,
    const float* __restrict__ dtp, const int* __restrict__ nstepsp,
    float* __restrict__ out) {
  __shared__ float sh[LDS_FLOATS];

  const int tx = threadIdx.x;
  const int tid = blockIdx.x * TPB + tx;   // 0 .. B*N-1
  const int bidx = tid >> 11;               // / N
  const int nidx = tid & (NN - 1);

  const float dt = dtp[0];
  const int nsteps = nstepsp[0];
  const float sqdt = sqrtf(dt);

  const float* xr = x + (size_t)bidx * ROWLEN;
  float t = xr[0];
  float y0 = xr[2 + nidx * 2 + 0];
  float y1 = xr[2 + nidx * 2 + 1];
  const float tcrit = xr[2 + NN * DD + 0];
  const float sp0 = xr[2 + NN * DD + 1];
  const float sp1 = xr[2 + NN * DD + 2];
  const float sq0 = xr[2 + NN * DD + 3];
  const float sq1 = xr[2 + NN * DD + 4];

  // Wt is (D, NSIG) row-major; tilt[d] = sum_s signals[s] * Wt[d][s]
  const float wt00 = Wt[0], wt01 = Wt[1], wt10 = Wt[2], wt11 = Wt[3];

  const uint32_t f0 = (uint32_t)(tid << 1);  // flat idx of component 0

#pragma unroll 1
  for (int i = 0; i < nsteps; ++i) {
    // per-step key: fold_in(key(42), i) = threefry((0,42), (0,i)); i uniform
    uint32_t k0, k1;
    tf2x32(0u, 42u, 0u, (uint32_t)i, k0, k1);

    // ---- layer 1: 2 -> 16 (rows of W1); stash h1 ----
    v16f h1;
#pragma unroll
    for (int j = 0; j < 16; ++j) {
      float z = fmaf(W1[2 * j + 0], y0, fmaf(W1[2 * j + 1], y1, b1[j]));
      float h = z > 0.0f ? z : (__expf(z) - 1.0f);
      h1[j] = h;
      sh[(SLOT_H1 + j) * TPB + tx] = h;
    }

    // ---- layer 2 (16->32) fused with z3 accumulation (32), 8-blocks ----
    // All W3 reads are contiguous 8-float row segments (s_load_dwordx8).
    // z3[jj] order: b3 first, then k = 0..31 ascending  (bit-identical to R4)
    v32f z3;
#pragma unroll
    for (int jb = 0; jb < 4; ++jb) {
      v8f h2b;
#pragma unroll
      for (int u = 0; u < 8; ++u) {
        const int j = jb * 8 + u;
        float z = b2[j];
#pragma unroll
        for (int k = 0; k < 16; ++k) z = fmaf(W2[16 * j + k], h1[k], z);
        float h = z > 0.0f ? z : (__expf(z) - 1.0f);
        h2b[u] = h;
        sh[(SLOT_H2 + j) * TPB + tx] = h;
      }
#pragma unroll
      for (int jj = 0; jj < 32; ++jj) {
        float acc = (jb == 0) ? b3[jj] : z3[jj];
#pragma unroll
        for (int u = 0; u < 8; ++u)
          acc = fmaf(W3[32 * jj + jb * 8 + u], h2b[u], acc);
        z3[jj] = acc;
      }
    }

    // ---- layer 3 activate fused with z4 accumulation (16), 8-blocks ----
    v16f z4;
#pragma unroll
    for (int jb = 0; jb < 4; ++jb) {
      v8f h3b;
#pragma unroll
      for (int u = 0; u < 8; ++u) {
        const int j = jb * 8 + u;
        float zz = z3[j];
        float h = zz > 0.0f ? zz : (__expf(zz) - 1.0f);
        h3b[u] = h;
        sh[(SLOT_H3 + j) * TPB + tx] = h;
      }
#pragma unroll
      for (int ii = 0; ii < 16; ++ii) {
        float acc = (jb == 0) ? b4[ii] : z4[ii];
#pragma unroll
        for (int u = 0; u < 8; ++u)
          acc = fmaf(W4[32 * ii + jb * 8 + u], h3b[u], acc);
        z4[ii] = acc;
      }
    }

    // ---- layer 4 activate + layer 5 + softplus' ----
    v16f h4;
#pragma unroll
    for (int j = 0; j < 16; ++j) {
      float zz = z4[j];
      h4[j] = zz > 0.0f ? zz : (__expf(zz) - 1.0f);
    }
    float z5 = b5[0];
#pragma unroll
    for (int k = 0; k < 16; ++k) z5 = fmaf(W5[k], h4[k], z5);
    float g5 = 1.0f / (1.0f + __expf(-z5));  // d softplus = sigmoid

    // ---- backward (input-gradient), all row-wise, input-incremental ----
    v16f g4;
#pragma unroll
    for (int k = 0; k < 16; ++k) g4[k] = W5[k] * g5 * DFROMH(h4[k]);

    // a3[k] = sum_{j=0..15} W4[j][k] * g4[j]   (rows of W4, j ascending)
    v32f a3;
#pragma unroll
    for (int j = 0; j < 16; ++j) {
#pragma unroll
      for (int k = 0; k < 32; ++k) {
        float w = W4[32 * j + k];
        a3[k] = (j == 0) ? w * g4[0] : fmaf(w, g4[j], a3[k]);
      }
    }
    // g3[j] = a3[j] * d3[j]; a2[k] = sum_j W3[j][k] * g3[j]  (rows of W3)
    v32f a2;
#pragma unroll
    for (int j = 0; j < 32; ++j) {
      float g3j = a3[j] * DFROMH(sh[(SLOT_H3 + j) * TPB + tx]);
#pragma unroll
      for (int k = 0; k < 32; ++k) {
        float w = W3[32 * j + k];
        a2[k] = (j == 0) ? w * g3j : fmaf(w, g3j, a2[k]);
      }
    }
    // g2[j] = a2[j] * d2[j]; a1[k] = sum_j W2[j][k] * g2[j]  (rows of W2)
    v16f a1;
#pragma unroll
    for (int j = 0; j < 32; ++j) {
      float g2j = a2[j] * DFROMH(sh[(SLOT_H2 + j) * TPB + tx]);
#pragma unroll
      for (int k = 0; k < 16; ++k) {
        float w = W2[16 * j + k];
        a1[k] = (j == 0) ? w * g2j : fmaf(w, g2j, a1[k]);
      }
    }
    // gy = W1^T (a1 * d1)
    float gy0 = 0.0f, gy1 = 0.0f;
#pragma unroll
    for (int j = 0; j < 16; ++j) {
      float g1j = a1[j] * DFROMH(sh[(SLOT_H1 + j) * TPB + tx]);
      gy0 = fmaf(W1[2 * j + 0], g1j, gy0);
      gy1 = fmaf(W1[2 * j + 1], g1j, gy1);
    }

    // ---- tilt ----
    bool pre = t < tcrit;
    float s0 = pre ? sp0 : sq0;
    float s1 = pre ? sp1 : sq1;
    float tilt0 = fmaf(s0, wt00, s1 * wt01);
    float tilt1 = fmaf(s0, wt10, s1 * wt11);

    // ---- noise (exact JAX threefry normal) ----
    float nz0 = jax_normal_elem(k0, k1, f0);
    float nz1 = jax_normal_elem(k0, k1, f0 + 1u);

    // ---- Euler-Maruyama update ----
    float drift0 = -(gy0 + tilt0);
    float drift1 = -(gy1 + tilt1);
    y0 = y0 + drift0 * dt + SIGMA_C * (nz0 * sqdt);
    y1 = y1 + drift1 * dt + SIGMA_C * (nz1 * sqdt);
    t += dt;
  }

  out[(size_t)tid * 2 + 0] = y0;
  out[(size_t)tid * 2 + 1] = y1;
}

extern "C" void kernel_launch(void* const* d_in, const int* in_sizes, int n_in,
                              void* d_out, int out_size, void* d_ws,
                              size_t ws_size, hipStream_t stream) {
  const float* x  = (const float*)d_in[0];
  const float* W1 = (const float*)d_in[1];
  const float* b1 = (const float*)d_in[2];
  const float* W2 = (const float*)d_in[3];
  const float* b2 = (const float*)d_in[4];
  const float* W3 = (const float*)d_in[5];
  const float* b3 = (const float*)d_in[6];
  const float* W4 = (const float*)d_in[7];
  const float* b4 = (const float*)d_in[8];
  const float* W5 = (const float*)d_in[9];
  const float* b5 = (const float*)d_in[10];
  const float* Wt = (const float*)d_in[11];
  const float* dt = (const float*)d_in[12];
  const int* nsteps = (const int*)d_in[13];
  float* out = (float*)d_out;

  dim3 grid((BB * NN) / TPB);
  dim3 block(TPB);
  hipLaunchKernelGGL(phinn_kernel, grid, block, 0, stream,
                     x, W1, b1, W2, b2, W3, b3, W4, b4, W5, b5, Wt, dt, nsteps,
                     out);
}